// Round 15
// baseline (379.254 us; speedup 1.0000x reference)
//
#include <hip/hip_runtime.h>
#include <hip/hip_bf16.h>

// B=2,S=2048 -> T=4096 tokens, D=1024, H=2048, E=8, top_k=2
#define TOK 4096
#define DD 1024
#define HH 2048
#define NE 8
#define RTOT (TOK * 2)
#define MAXT1 72   // max Sum ceil(ne/128) = 64 + 7 (+1 pad)

typedef __attribute__((ext_vector_type(8))) short bf16x8;
typedef __attribute__((ext_vector_type(4))) float f32x4;
typedef __attribute__((ext_vector_type(4))) unsigned int u32x4;

static __device__ __forceinline__ unsigned short f2bf(float f) {
  union { float f; unsigned int u; } v; v.f = f;
  unsigned int r = v.u + 0x7fffu + ((v.u >> 16) & 1u);
  return (unsigned short)(r >> 16);
}

// async global->LDS, 16B/lane; LDS dest = wave-uniform base + lane*16
static __device__ __forceinline__ void gload16(const unsigned short* g, unsigned short* l) {
  __builtin_amdgcn_global_load_lds(
      (const __attribute__((address_space(1))) unsigned int*)g,
      (__attribute__((address_space(3))) unsigned int*)l, 16, 0, 0);
}

// packed f32x2 -> bf16x2 (RNE), single HW instruction
#define CVT(d, lo, hi) asm("v_cvt_pk_bf16_f32 %0, %1, %2" : "=v"(d) : "v"(lo), "v"(hi))

// non-temporal stores: no write-allocate (R13 finding: FETCH==WRITE -> every
// streaming store line was fetched from HBM before overwrite).
// __builtin_nontemporal_store needs true vector types, not HIP's struct uint4.
static __device__ __forceinline__ void nts16(unsigned short* p, uint4 v) {
  u32x4 t; t.x = v.x; t.y = v.y; t.z = v.z; t.w = v.w;
  __builtin_nontemporal_store(t, (u32x4*)p);
}
static __device__ __forceinline__ void ntsu32(unsigned int* p, unsigned int v) {
  __builtin_nontemporal_store(v, p);
}
static __device__ __forceinline__ void ntsu16(unsigned short* p, unsigned short v) {
  __builtin_nontemporal_store(v, p);
}

#define BARX() do { asm volatile("" ::: "memory"); __builtin_amdgcn_s_barrier(); asm volatile("" ::: "memory"); } while (0)
#define VMCNT8() asm volatile("s_waitcnt vmcnt(8)" ::: "memory")
#define VMCNT0() asm volatile("s_waitcnt vmcnt(0)" ::: "memory")

// ---------------- fused pre-kernel: router (blocks 0..1023) + transpose (1024..4095) ----
__global__ __launch_bounds__(256) void pre_k(
    const float* __restrict__ x, const float* __restrict__ gw,
    unsigned short* __restrict__ xb, int* __restrict__ topi, float* __restrict__ topp,
    int* __restrict__ counts,
    const float* __restrict__ w1, const float* __restrict__ w2, const float* __restrict__ w3,
    unsigned short* __restrict__ wgu, unsigned short* __restrict__ w3t) {
  __shared__ unsigned short tbuf[2][64 * 72];
  const int tid = threadIdx.x;
  const int lane = tid & 63, wv = tid >> 6;

  if (blockIdx.x < 1024) {
    // ---- router ----
    const int t = blockIdx.x * 4 + wv;
    const float4* xr = (const float4*)(x + (size_t)t * DD);
    unsigned int* xw = (unsigned int*)(xb + (size_t)t * DD);
    float acc[NE];
#pragma unroll
    for (int e = 0; e < NE; ++e) acc[e] = 0.f;
#pragma unroll
    for (int i = 0; i < 4; ++i) {
      const float4 xv = xr[i * 64 + lane];
      unsigned int p0, p1;
      CVT(p0, xv.x, xv.y);
      CVT(p1, xv.z, xv.w);
      ntsu32(&xw[(i * 64 + lane) * 2], p0);
      ntsu32(&xw[(i * 64 + lane) * 2 + 1], p1);
#pragma unroll
      for (int e = 0; e < NE; ++e) {
        const float4 gv = ((const float4*)(gw + (size_t)e * DD))[i * 64 + lane];
        acc[e] += xv.x * gv.x + xv.y * gv.y + xv.z * gv.z + xv.w * gv.w;
      }
    }
#pragma unroll
    for (int e = 0; e < NE; ++e)
#pragma unroll
      for (int s = 32; s > 0; s >>= 1) acc[e] += __shfl_xor(acc[e], s, 64);
    if (lane == 0) {
      int i0 = 0; float v0 = acc[0];
#pragma unroll
      for (int e = 1; e < NE; ++e) if (acc[e] > v0) { v0 = acc[e]; i0 = e; }
      int i1 = -1; float v1 = -1e30f;
#pragma unroll
      for (int e = 0; e < NE; ++e) if (e != i0 && acc[e] > v1) { v1 = acc[e]; i1 = e; }
      const float ex = __expf(v1 - v0);
      const float inv = 1.f / (1.f + ex);
      topi[t * 2] = i0; topi[t * 2 + 1] = i1;
      topp[t * 2] = inv; topp[t * 2 + 1] = ex * inv;
      atomicAdd(&counts[i0], 1); atomicAdd(&counts[i1], 1);
    }
    return;
  }

  // ---- transpose: 4 column-adjacent 64x64 tiles per block, pipelined ----
  const int bid = blockIdx.x - 1024;
  const float* in;
  int C, r0, c0base, e, mat;
  bool isGU;
  if (bid < 2048) {            // w1/w2 -> wgu
    const int me = bid >> 7;   // 0..15
    mat = me >> 3; e = me & 7;
    const int w = bid & 127;
    const int tr = w >> 3, tcg = w & 7;   // 16 tr x 8 tile-groups
    in = (mat ? w2 : w1) + (size_t)e * DD * HH;
    C = HH; r0 = tr * 64; c0base = tcg * 256;
    isGU = true;
  } else {                     // w3 -> w3t
    const int b2 = bid - 2048;
    e = b2 >> 7; mat = 2;
    const int w = b2 & 127;
    const int tr = w >> 2, tcg = w & 3;   // 32 tr x 4 tile-groups
    in = w3 + (size_t)e * HH * DD;
    C = DD; r0 = tr * 64; c0base = tcg * 256;
    isGU = false;
  }

  const int rs = tid >> 4, cs = tid & 15;
  const float* tbase = in + (size_t)(r0 + rs) * C + c0base + cs * 4;
  float4 ra[4], rb[4];

#define TLOAD(R, ti)                                                      \
  do {                                                                    \
    _Pragma("unroll")                                                     \
    for (int j = 0; j < 4; ++j)                                           \
      R[j] = *(const float4*)(tbase + (size_t)(j * 16) * C + (ti) * 64);  \
  } while (0)

#define TSTAGE(R, bs)                                                     \
  do {                                                                    \
    _Pragma("unroll")                                                     \
    for (int j = 0; j < 4; ++j) {                                         \
      unsigned int d0, d1;                                                \
      CVT(d0, R[j].x, R[j].y);                                            \
      CVT(d1, R[j].z, R[j].w);                                            \
      unsigned short* tb = &tbuf[bs][(cs * 4) * 72 + rs + j * 16];        \
      tb[0] = (unsigned short)d0;                                         \
      tb[72] = (unsigned short)(d0 >> 16);                                \
      tb[144] = (unsigned short)d1;                                       \
      tb[216] = (unsigned short)(d1 >> 16);                               \
    }                                                                     \
  } while (0)

#define TSTORE(bs, ti)                                                    \
  do {                                                                    \
    const int c0 = c0base + (ti) * 64;                                    \
    _Pragma("unroll")                                                     \
    for (int q = 0; q < 2; ++q) {                                         \
      const int idx = q * 256 + tid;                                      \
      const int crow = idx >> 3, seg = idx & 7;                           \
      const uint4 val = *(const uint4*)&tbuf[bs][crow * 72 + seg * 8];    \
      if (isGU) {                                                         \
        const int j = c0 + crow;                                          \
        const int R_ = ((j >> 4) << 5) + (j & 15) + mat * 16;             \
        nts16(&wgu[((size_t)e * 2 * HH + R_) * DD + r0 + seg * 8], val);  \
      } else {                                                            \
        nts16(&w3t[((size_t)e * DD + c0 + crow) * HH + r0 + seg * 8], val); \
      }                                                                   \
    }                                                                     \
  } while (0)

  TLOAD(ra, 0);
  TLOAD(rb, 1);
  TSTAGE(ra, 0); __syncthreads(); TSTORE(0, 0);
  TLOAD(ra, 2);
  TSTAGE(rb, 1); __syncthreads(); TSTORE(1, 1);
  TLOAD(rb, 3);
  TSTAGE(ra, 0); __syncthreads(); TSTORE(0, 2);
  TSTAGE(rb, 1); __syncthreads(); TSTORE(1, 3);
#undef TLOAD
#undef TSTAGE
#undef TSTORE
}

// ---------------- deterministic sorted compaction (ballot prefix-scan) ----------------
__global__ __launch_bounds__(256) void compact_k(
    const int* __restrict__ topi, const float* __restrict__ topp,
    const int* __restrict__ counts, int* __restrict__ perm, float* __restrict__ prow) {
  const int e = blockIdx.x;
  const int tid = threadIdx.x, lane = tid & 63, wv = tid >> 6;
  __shared__ int wsum[4];
  __shared__ int cbase;
  if (tid == 0) {
    int b = 0;
    for (int i = 0; i < e; ++i) b += counts[i];
    cbase = b;
  }
  __syncthreads();
  for (int c0 = 0; c0 < TOK; c0 += 256) {
    const int t = c0 + tid;
    const int a = topi[2 * t], b = topi[2 * t + 1];
    const int k = (a == e) ? 0 : ((b == e) ? 1 : -1);
    const unsigned long long bal = __ballot(k >= 0);
    const int rank = __popcll(bal & ((1ull << lane) - 1ull));
    if (lane == 0) wsum[wv] = __popcll(bal);
    __syncthreads();
    int woff = 0;
#pragma unroll
    for (int i = 0; i < 4; ++i) if (i < wv) woff += wsum[i];
    const int ctot = wsum[0] + wsum[1] + wsum[2] + wsum[3];
    if (k >= 0) {
      const int pos = cbase + woff + rank;
      perm[pos] = t;
      prow[pos] = topp[2 * t + k];
    }
    __syncthreads();
    if (tid == 0) cbase += ctot;
    __syncthreads();
  }
}

// ---- inline tile decode (BM=128): tix -> (e, m0, off, ne); false if dead ----
static __device__ __forceinline__ bool decode128(const int* counts, int tix,
                                                 int& e, int& m0, int& off, int& ne) {
  int t = tix; off = 0;
  for (e = 0; e < NE; ++e) {
    const int c = counts[e];
    const int nt = (c + 127) >> 7;
    if (t < nt) { m0 = t << 7; ne = c; return true; }
    t -= nt; off += c;
  }
  return false;
}

// ---------------- GEMM1: X(gathered bf16) @ wgu(bf16) -> h = silu(g)*u ----------------
// BM=128, BN=128 wgu-rows (64 h-cols), BK=64; 4 waves (2x2); depth-2 counted-vmcnt dbuf.
__global__ __launch_bounds__(256) void gemm1_k(
    const unsigned short* __restrict__ Xb, const unsigned short* __restrict__ wgu,
    const int* __restrict__ counts, const int* __restrict__ perm,
    unsigned short* __restrict__ hbuf) {
  const int bx = blockIdx.x & 31;
  int e, m0, off, ne;
  if (!decode128(counts, blockIdx.x >> 5, e, m0, off, ne)) return;

  __shared__ unsigned short As[2][128 * 64];
  __shared__ unsigned short Bs[2][128 * 64];

  const int tid = threadIdx.x, lane = tid & 63, wv = tid >> 6;
  const int srow = lane >> 3;
  const int schunk = ((lane & 7) ^ srow) * 8;

  const unsigned short* pA[4];
  const unsigned short* pB[4];
#pragma unroll
  for (int q = 0; q < 4; ++q) {
    const int row = wv * 32 + q * 8 + srow;
    pA[q] = Xb + (size_t)perm[off + min(m0 + row, ne - 1)] * DD + schunk;
    pB[q] = wgu + ((size_t)e * 2 * HH + bx * 128 + row) * DD + schunk;
  }

  const int wr = wv >> 1, wc = wv & 1;
  const int lr = lane & 15, kc = lane >> 4;

  f32x4 acc[4][4];
#pragma unroll
  for (int a = 0; a < 4; ++a)
#pragma unroll
    for (int b = 0; b < 4; ++b) acc[a][b] = f32x4{0.f, 0.f, 0.f, 0.f};

#define G1_ISSUE(b)                                                       \
  do {                                                                    \
    _Pragma("unroll")                                                     \
    for (int q = 0; q < 4; ++q) {                                         \
      gload16(pA[q], &As[b][(wv * 32 + q * 8) * 64]); pA[q] += 64;        \
      gload16(pB[q], &Bs[b][(wv * 32 + q * 8) * 64]); pB[q] += 64;        \
    }                                                                     \
  } while (0)

#define G1_COMPUTE(b)                                                     \
  do {                                                                    \
    _Pragma("unroll")                                                     \
    for (int kk = 0; kk < 2; ++kk) {                                      \
      bf16x8 af[4], bf[4];                                                \
      _Pragma("unroll")                                                   \
      for (int mf = 0; mf < 4; ++mf)                                      \
        af[mf] = *(const bf16x8*)&As[b][(wr * 64 + mf * 16 + lr) * 64 +   \
                                       ((kk * 4 + kc) ^ (lr & 7)) * 8];   \
      _Pragma("unroll")                                                   \
      for (int nf = 0; nf < 4; ++nf)                                      \
        bf[nf] = *(const bf16x8*)&Bs[b][(wc * 64 + nf * 16 + lr) * 64 +   \
                                       ((kk * 4 + kc) ^ (lr & 7)) * 8];   \
      _Pragma("unroll")                                                   \
      for (int mf = 0; mf < 4; ++mf)                                      \
        _Pragma("unroll")                                                 \
        for (int nf = 0; nf < 4; ++nf)                                    \
          acc[mf][nf] = __builtin_amdgcn_mfma_f32_16x16x32_bf16(          \
              af[mf], bf[nf], acc[mf][nf], 0, 0, 0);                      \
    }                                                                     \
  } while (0)

  G1_ISSUE(0);
  G1_ISSUE(1);
  VMCNT8(); BARX();
  for (int t = 0; t < DD / 64; ++t) {
    const int cur = t & 1;
    G1_COMPUTE(cur);
    if (t == DD / 64 - 1) break;
    BARX();                                  // all waves done reading buf[cur]
    if (t < DD / 64 - 2) { G1_ISSUE(cur); VMCNT8(); }   // tile t+2 in; wait t+1
    else VMCNT0();
    BARX();                                  // tile t+1 visible
  }

  // epilogue: nf even = G, nf odd = U (same 16 h-cols)
#pragma unroll
  for (int mf = 0; mf < 4; ++mf)
#pragma unroll
    for (int np = 0; np < 2; ++np) {
      const f32x4 g = acc[mf][2 * np], u = acc[mf][2 * np + 1];
      const int hcol = bx * 64 + (wc * 2 + np) * 16 + lr;
#pragma unroll
      for (int r = 0; r < 4; ++r) {
        const int rl = m0 + wr * 64 + mf * 16 + kc * 4 + r;
        if (rl < ne) {
          const float gg = g[r], uu = u[r];
          const float hv = gg / (1.f + __expf(-gg)) * uu;
          ntsu16(&hbuf[(size_t)(off + rl) * HH + hcol], f2bf(hv));
        }
      }
    }
#undef G1_ISSUE
#undef G1_COMPUTE
}

// ---------------- GEMM2: h(bf16) @ w3t(bf16) * prob -> atomicAdd into out ----------------
// BM=128, BN=128, BK=64; 4 waves (2x2); depth-2 counted-vmcnt dbuf; K=2048.
__global__ __launch_bounds__(256) void gemm2_k(
    const unsigned short* __restrict__ hbuf, const unsigned short* __restrict__ w3t,
    const int* __restrict__ counts, const int* __restrict__ perm,
    const float* __restrict__ prow, float* __restrict__ out) {
  const int bx = blockIdx.x & 7;
  int e, m0, off, ne;
  if (!decode128(counts, blockIdx.x >> 3, e, m0, off, ne)) return;
  const int n1 = bx * 128;

  __shared__ unsigned short As[2][128 * 64];
  __shared__ unsigned short Bs[2][128 * 64];

  const int tid = threadIdx.x, lane = tid & 63, wv = tid >> 6;
  const int srow = lane >> 3;
  const int schunk = ((lane & 7) ^ srow) * 8;

  const unsigned short* pA[4];
  const unsigned short* pB[4];
#pragma unroll
  for (int q = 0; q < 4; ++q) {
    const int row = wv * 32 + q * 8 + srow;
    pA[q] = hbuf + (size_t)(off + min(m0 + row, ne - 1)) * HH + schunk;
    pB[q] = w3t + ((size_t)e * DD + n1 + row) * HH + schunk;
  }

  const int wr = wv >> 1, wc = wv & 1;
  const int lr = lane & 15, kc = lane >> 4;

  f32x4 acc[4][4];
#pragma unroll
  for (int a = 0; a < 4; ++a)
#pragma unroll
    for (int b = 0; b < 4; ++b) acc[a][b] = f32x4{0.f, 0.f, 0.f, 0.f};

#define G2_ISSUE(b)                                                       \
  do {                                                                    \
    _Pragma("unroll")                                                     \
    for (int q = 0; q < 4; ++q) {                                         \
      gload16(pA[q], &As[b][(wv * 32 + q * 8) * 64]); pA[q] += 64;        \
      gload16(pB[q], &Bs[b][(wv * 32 + q * 8) * 64]); pB[q] += 64;        \
    }                                                                     \
  } while (0)

#define G2_COMPUTE(b)                                                     \
  do {                                                                    \
    _Pragma("unroll")                                                     \
    for (int kk = 0; kk < 2; ++kk) {                                      \
      bf16x8 af[4], bf[4];                                                \
      _Pragma("unroll")                                                   \
      for (int mf = 0; mf < 4; ++mf)                                      \
        af[mf] = *(const bf16x8*)&As[b][(wr * 64 + mf * 16 + lr) * 64 +   \
                                       ((kk * 4 + kc) ^ (lr & 7)) * 8];   \
      _Pragma("unroll")                                                   \
      for (int nf = 0; nf < 4; ++nf)                                      \
        bf[nf] = *(const bf16x8*)&Bs[b][(wc * 64 + nf * 16 + lr) * 64 +   \
                                       ((kk * 4 + kc) ^ (lr & 7)) * 8];   \
      _Pragma("unroll")                                                   \
      for (int mf = 0; mf < 4; ++mf)                                      \
        _Pragma("unroll")                                                 \
        for (int nf = 0; nf < 4; ++nf)                                    \
          acc[mf][nf] = __builtin_amdgcn_mfma_f32_16x16x32_bf16(          \
              af[mf], bf[nf], acc[mf][nf], 0, 0, 0);                      \
    }                                                                     \
  } while (0)

  G2_ISSUE(0);
  G2_ISSUE(1);
  VMCNT8(); BARX();
  for (int t = 0; t < HH / 64; ++t) {
    const int cur = t & 1;
    G2_COMPUTE(cur);
    if (t == HH / 64 - 1) break;
    BARX();
    if (t < HH / 64 - 2) { G2_ISSUE(cur); VMCNT8(); }
    else VMCNT0();
    BARX();
  }

  // epilogue: out[tok] += prob * acc  (fp32 atomic add, commutative -> deterministic)
#pragma unroll
  for (int mf = 0; mf < 4; ++mf)
#pragma unroll
    for (int r = 0; r < 4; ++r) {
      const int rl = m0 + wr * 64 + mf * 16 + kc * 4 + r;
      if (rl < ne) {
        const int tok = perm[off + rl];
        const float p = prow[off + rl];
        float* op = out + (size_t)tok * DD + n1 + wc * 64 + lr;
#pragma unroll
        for (int nf = 0; nf < 4; ++nf)
          atomicAdd(op + nf * 16, p * acc[mf][nf][r]);
      }
    }
#undef G2_ISSUE
#undef G2_COMPUTE
}

// ---------------- workspace layout ----------------
#define WS_COUNTS 0
#define WS_TOPI 128
#define WS_TOPP (WS_TOPI + TOK * 2 * 4)
#define WS_PERM (WS_TOPP + TOK * 2 * 4)
#define WS_PROW (WS_PERM + RTOT * 4)
#define WS_XB ((WS_PROW + RTOT * 4 + 255) & ~(size_t)255)
#define WS_H (WS_XB + (size_t)TOK * DD * 2)
#define WS_WGU (WS_H + (size_t)RTOT * HH * 2)
#define WS_W3T (WS_WGU + (size_t)NE * 2 * HH * DD * 2)
// end = WS_W3T + NE*DD*HH*2 ~= 136 MB

extern "C" void kernel_launch(void* const* d_in, const int* in_sizes, int n_in,
                              void* d_out, int out_size, void* d_ws, size_t ws_size,
                              hipStream_t stream) {
  const float* x = (const float*)d_in[0];
  const float* gw = (const float*)d_in[1];
  const float* w1 = (const float*)d_in[2];
  const float* w2 = (const float*)d_in[3];
  const float* w3 = (const float*)d_in[4];
  float* out = (float*)d_out;
  char* ws = (char*)d_ws;

  int* counts = (int*)(ws + WS_COUNTS);
  int* topi = (int*)(ws + WS_TOPI);
  float* topp = (float*)(ws + WS_TOPP);
  int* perm = (int*)(ws + WS_PERM);
  float* prow = (float*)(ws + WS_PROW);
  unsigned short* Xb = (unsigned short*)(ws + WS_XB);
  unsigned short* hbuf = (unsigned short*)(ws + WS_H);
  unsigned short* wgu = (unsigned short*)(ws + WS_WGU);
  unsigned short* w3t = (unsigned short*)(ws + WS_W3T);

  hipMemsetAsync(ws, 0, 128, stream);
  hipMemsetAsync(out, 0, (size_t)out_size * sizeof(float), stream);
  // fused router (1024 blocks) + pipelined 4-tile weight transpose (3072 blocks)
  pre_k<<<1024 + 3072, 256, 0, stream>>>(x, gw, Xb, topi, topp, counts,
                                         w1, w2, w3, wgu, w3t);
  compact_k<<<NE, 256, 0, stream>>>(topi, topp, counts, perm, prow);
  gemm1_k<<<MAXT1 * 32, 256, 0, stream>>>(Xb, wgu, counts, perm, hbuf);
  gemm2_k<<<MAXT1 * 8, 256, 0, stream>>>(hbuf, w3t, counts, perm, prow, out);
}

// Round 16
// 378.753 us; speedup vs baseline: 1.0013x; 1.0013x over previous
//
#include <hip/hip_runtime.h>
#include <hip/hip_bf16.h>

// B=2,S=2048 -> T=4096 tokens, D=1024, H=2048, E=8, top_k=2
#define TOK 4096
#define DD 1024
#define HH 2048
#define NE 8
#define RTOT (TOK * 2)
#define MAXT1 72   // max Sum ceil(ne/128) = 64 + 7 (+1 pad)

typedef __attribute__((ext_vector_type(8))) short bf16x8;
typedef __attribute__((ext_vector_type(4))) float f32x4;
typedef __attribute__((ext_vector_type(2))) unsigned int u32x2;

static __device__ __forceinline__ unsigned short f2bf(float f) {
  union { float f; unsigned int u; } v; v.f = f;
  unsigned int r = v.u + 0x7fffu + ((v.u >> 16) & 1u);
  return (unsigned short)(r >> 16);
}

// async global->LDS, 16B/lane; LDS dest = wave-uniform base + lane*16
static __device__ __forceinline__ void gload16(const unsigned short* g, unsigned short* l) {
  __builtin_amdgcn_global_load_lds(
      (const __attribute__((address_space(1))) unsigned int*)g,
      (__attribute__((address_space(3))) unsigned int*)l, 16, 0, 0);
}

// packed f32x2 -> bf16x2 (RNE), single HW instruction
#define CVT(d, lo, hi) asm("v_cvt_pk_bf16_f32 %0, %1, %2" : "=v"(d) : "v"(lo), "v"(hi))

#define BARX() do { asm volatile("" ::: "memory"); __builtin_amdgcn_s_barrier(); asm volatile("" ::: "memory"); } while (0)
#define VMCNT(n) asm volatile("s_waitcnt vmcnt(" #n ")" ::: "memory")
#define LGKM0() asm volatile("s_waitcnt lgkmcnt(0)" ::: "memory")

// ---------------- router: fp32 scores, top-2 softmax; emits Xb (bf16 x) ----------------
__global__ void router_k(const float* __restrict__ x, const float* __restrict__ gw,
                         unsigned short* __restrict__ xb,
                         int* __restrict__ topi, float* __restrict__ topp,
                         int* __restrict__ counts) {
  const int lane = threadIdx.x & 63;
  const int t = blockIdx.x * 4 + (threadIdx.x >> 6);
  const float4* xr = (const float4*)(x + (size_t)t * DD);
  unsigned int* xw = (unsigned int*)(xb + (size_t)t * DD);
  float acc[NE];
#pragma unroll
  for (int e = 0; e < NE; ++e) acc[e] = 0.f;
#pragma unroll
  for (int i = 0; i < 4; ++i) {
    const float4 xv = xr[i * 64 + lane];
    unsigned int p0, p1;
    CVT(p0, xv.x, xv.y);
    CVT(p1, xv.z, xv.w);
    xw[(i * 64 + lane) * 2] = p0;
    xw[(i * 64 + lane) * 2 + 1] = p1;
#pragma unroll
    for (int e = 0; e < NE; ++e) {
      const float4 gv = ((const float4*)(gw + (size_t)e * DD))[i * 64 + lane];
      acc[e] += xv.x * gv.x + xv.y * gv.y + xv.z * gv.z + xv.w * gv.w;
    }
  }
#pragma unroll
  for (int e = 0; e < NE; ++e)
#pragma unroll
    for (int s = 32; s > 0; s >>= 1) acc[e] += __shfl_xor(acc[e], s, 64);
  if (lane == 0) {
    int i0 = 0; float v0 = acc[0];
#pragma unroll
    for (int e = 1; e < NE; ++e) if (acc[e] > v0) { v0 = acc[e]; i0 = e; }
    int i1 = -1; float v1 = -1e30f;
#pragma unroll
    for (int e = 0; e < NE; ++e) if (e != i0 && acc[e] > v1) { v1 = acc[e]; i1 = e; }
    const float ex = __expf(v1 - v0);
    const float inv = 1.f / (1.f + ex);
    topi[t * 2] = i0; topi[t * 2 + 1] = i1;
    topp[t * 2] = inv; topp[t * 2 + 1] = ex * inv;
    atomicAdd(&counts[i0], 1); atomicAdd(&counts[i1], 1);
  }
}

// ---------------- deterministic sorted compaction (ballot prefix-scan) ----------------
__global__ __launch_bounds__(256) void compact_k(
    const int* __restrict__ topi, const float* __restrict__ topp,
    const int* __restrict__ counts, int* __restrict__ perm, float* __restrict__ prow) {
  const int e = blockIdx.x;
  const int tid = threadIdx.x, lane = tid & 63, wv = tid >> 6;
  __shared__ int wsum[4];
  __shared__ int cbase;
  if (tid == 0) {
    int b = 0;
    for (int i = 0; i < e; ++i) b += counts[i];
    cbase = b;
  }
  __syncthreads();
  for (int c0 = 0; c0 < TOK; c0 += 256) {
    const int t = c0 + tid;
    const int a = topi[2 * t], b = topi[2 * t + 1];
    const int k = (a == e) ? 0 : ((b == e) ? 1 : -1);
    const unsigned long long bal = __ballot(k >= 0);
    const int rank = __popcll(bal & ((1ull << lane) - 1ull));
    if (lane == 0) wsum[wv] = __popcll(bal);
    __syncthreads();
    int woff = 0;
#pragma unroll
    for (int i = 0; i < 4; ++i) if (i < wv) woff += wsum[i];
    const int ctot = wsum[0] + wsum[1] + wsum[2] + wsum[3];
    if (k >= 0) {
      const int pos = cbase + woff + rank;
      perm[pos] = t;
      prow[pos] = topp[2 * t + k];
    }
    __syncthreads();
    if (tid == 0) cbase += ctot;
    __syncthreads();
  }
}

// ---- inline tile decode (BM=128): tix -> (e, m0, off, ne); false if dead ----
static __device__ __forceinline__ bool decode128(const int* counts, int tix,
                                                 int& e, int& m0, int& off, int& ne) {
  int t = tix; off = 0;
  for (e = 0; e < NE; ++e) {
    const int c = counts[e];
    const int nt = (c + 127) >> 7;
    if (t < nt) { m0 = t << 7; ne = c; return true; }
    t -= nt; off += c;
  }
  return false;
}

// ==== B-staging helpers (in-GEMM fp32->bf16 transpose; replaces the 150us pre_k) ====
// Thread owns a [4k][4n] microblock: 4 coalesced float4 row-loads, cvt_pk packs k-pairs,
// 4x ds_write_b64 into [n][k] LDS tile (stride 72 shorts, kb-XOR swizzle, ~2-way banks).
// Read side: bf16x8 at row*72 + ((kchunk ^ ((row>>2)&7))*8  (16B aligned).

// pack one n-column c of the microblock and write 8B to LDS
#define BPACK1(Vv, COMP, c_, base_)                                       \
  do {                                                                    \
    unsigned int a_, b_;                                                  \
    CVT(a_, Vv[0].COMP, Vv[1].COMP);                                      \
    CVT(b_, Vv[2].COMP, Vv[3].COMP);                                      \
    const int row_ = 4 * nb + (c_);                                       \
    const int kbp_ = kb ^ ((nb & 7) << 1);                                \
    u32x2 w_; w_.x = a_; w_.y = b_;                                       \
    *(u32x2*)&lds[(base_) + row_ * 72 + kbp_ * 4] = w_;                   \
  } while (0)

#define BPACK4(Vv, base_)                                                 \
  do {                                                                    \
    BPACK1(Vv, x, 0, base_); BPACK1(Vv, y, 1, base_);                     \
    BPACK1(Vv, z, 2, base_); BPACK1(Vv, w, 3, base_);                     \
  } while (0)

// ---------------- GEMM1: X(gathered bf16) @ w1,w2(fp32, transposed in-kernel) ----------------
// BM=128, 64 h-cols per block (Bs1=G, Bs2=U), BK=64; 4 waves (2Mx2N).
// Counted-vmcnt depth-2: per ISSUE = 8 B-reg-loads + 4 A-gloads; VMCNT(4)->write B, VMCNT(12)->compute.
__global__ __launch_bounds__(256) void gemm1_k(
    const unsigned short* __restrict__ Xb, const float* __restrict__ w1,
    const float* __restrict__ w2, const int* __restrict__ counts,
    const int* __restrict__ perm, unsigned short* __restrict__ hbuf) {
  const int bx = blockIdx.x & 31;
  int e, m0, off, ne;
  if (!decode128(counts, blockIdx.x >> 5, e, m0, off, ne)) return;

  extern __shared__ __align__(16) unsigned short lds[];
  // shorts: A buf b: b*8192 ; B(buf b, mat m): 16384 + b*9216 + m*4608  (total 69632 B)

  const int tid = threadIdx.x, lane = tid & 63, wv = tid >> 6;
  const int srow = lane >> 3;
  const int schunk = ((lane & 7) ^ srow) * 8;
  const int n0 = bx * 64;

  // A pointers (gathered rows)
  const unsigned short* pA[4];
#pragma unroll
  for (int q = 0; q < 4; ++q) {
    const int row = wv * 32 + q * 8 + srow;
    pA[q] = Xb + (size_t)perm[off + min(m0 + row, ne - 1)] * DD + schunk;
  }
  // B pointers: microblock (kb,nb)
  const int kb = tid >> 4, nb = tid & 15;
  const float* pB1 = w1 + ((size_t)e * DD + 4 * kb) * HH + n0 + 4 * nb;
  const float* pB2 = w2 + ((size_t)e * DD + 4 * kb) * HH + n0 + 4 * nb;

  const int wr = wv >> 1, wc = wv & 1;
  const int lr = lane & 15, kc = lane >> 4;

  f32x4 acc[4][4];
#pragma unroll
  for (int a = 0; a < 4; ++a)
#pragma unroll
    for (int b = 0; b < 4; ++b) acc[a][b] = f32x4{0.f, 0.f, 0.f, 0.f};

  float4 B1v[4], B2v[4];

#define G1_ISSUE_B()                                                      \
  do {                                                                    \
    B1v[0] = *(const float4*)(pB1);                                       \
    B1v[1] = *(const float4*)(pB1 + HH);                                  \
    B1v[2] = *(const float4*)(pB1 + 2 * HH);                              \
    B1v[3] = *(const float4*)(pB1 + 3 * HH);                              \
    B2v[0] = *(const float4*)(pB2);                                       \
    B2v[1] = *(const float4*)(pB2 + HH);                                  \
    B2v[2] = *(const float4*)(pB2 + 2 * HH);                              \
    B2v[3] = *(const float4*)(pB2 + 3 * HH);                              \
    pB1 += (size_t)64 * HH; pB2 += (size_t)64 * HH;                       \
  } while (0)

#define G1_ISSUE_A(b)                                                     \
  do {                                                                    \
    _Pragma("unroll")                                                     \
    for (int q = 0; q < 4; ++q) {                                         \
      gload16(pA[q], lds + (b) * 8192 + (wv * 32 + q * 8) * 64);          \
      pA[q] += 64;                                                        \
    }                                                                     \
  } while (0)

#define G1_WRITE_B(b)                                                     \
  do {                                                                    \
    BPACK4(B1v, 16384 + (b) * 9216);                                      \
    BPACK4(B2v, 16384 + (b) * 9216 + 4608);                               \
  } while (0)

#define G1_COMPUTE(b)                                                     \
  do {                                                                    \
    const unsigned short* Ab = lds + (b) * 8192;                          \
    const unsigned short* Bg = lds + 16384 + (b) * 9216;                  \
    const unsigned short* Bu = Bg + 4608;                                 \
    _Pragma("unroll")                                                     \
    for (int kk = 0; kk < 2; ++kk) {                                      \
      bf16x8 af[4], bg[2], bu[2];                                         \
      _Pragma("unroll")                                                   \
      for (int mf = 0; mf < 4; ++mf)                                      \
        af[mf] = *(const bf16x8*)&Ab[(wr * 64 + mf * 16 + lr) * 64 +      \
                                     ((kk * 4 + kc) ^ (lr & 7)) * 8];     \
      _Pragma("unroll")                                                   \
      for (int np = 0; np < 2; ++np) {                                    \
        const int row = wc * 32 + np * 16 + lr;                           \
        const int so = row * 72 + ((kk * 4 + kc) ^ ((row >> 2) & 7)) * 8; \
        bg[np] = *(const bf16x8*)&Bg[so];                                 \
        bu[np] = *(const bf16x8*)&Bu[so];                                 \
      }                                                                   \
      _Pragma("unroll")                                                   \
      for (int mf = 0; mf < 4; ++mf)                                      \
        _Pragma("unroll")                                                 \
        for (int np = 0; np < 2; ++np) {                                  \
          acc[mf][2 * np] = __builtin_amdgcn_mfma_f32_16x16x32_bf16(      \
              af[mf], bg[np], acc[mf][2 * np], 0, 0, 0);                  \
          acc[mf][2 * np + 1] = __builtin_amdgcn_mfma_f32_16x16x32_bf16(  \
              af[mf], bu[np], acc[mf][2 * np + 1], 0, 0, 0);              \
        }                                                                 \
    }                                                                     \
  } while (0)

  // prologue: tiles 0,1 in flight
  G1_ISSUE_B(); G1_ISSUE_A(0);      // B0(8), A0(4)
  {
    float4 C1v[4], C2v[4];
#pragma unroll
    for (int j = 0; j < 4; ++j) { C1v[j] = B1v[j]; C2v[j] = B2v[j]; }
    G1_ISSUE_B(); G1_ISSUE_A(1);    // B1(8), A1(4): outstanding 24
    VMCNT(16);                      // B0 regs (in C1v/C2v copies? no: B0 already copied)
    // NOTE: C1v/C2v captured B0's register values BEFORE reissue; but the copies
    // happened before B1 loads overwrote B1v -- compiler orders the copy after the
    // load-use dependency (vmcnt inserted by compiler on copy). Write B0:
    BPACK4(C1v, 16384);
    BPACK4(C2v, 16384 + 4608);
  }
  VMCNT(12);                        // A0 landed
  LGKM0(); BARX();

  const int NT = DD / 64;
  for (int t = 0; t < NT; ++t) {
    const int cur = t & 1;
    G1_COMPUTE(cur);
    if (t == NT - 1) break;
    BARX();
    VMCNT(4);                       // B(t+1) regs ready (A(t+1) may fly)
    G1_WRITE_B(cur ^ 1);            // stage B(t+1)
    if (t + 2 < NT) { G1_ISSUE_B(); G1_ISSUE_A(cur); VMCNT(12); }
    else VMCNT(0);
    LGKM0(); BARX();
  }

  // epilogue: acc[mf][2np]=G, [2np+1]=U; hcol = bx*64 + wc*32 + np*16 + lr
#pragma unroll
  for (int mf = 0; mf < 4; ++mf)
#pragma unroll
    for (int np = 0; np < 2; ++np) {
      const f32x4 g = acc[mf][2 * np], u = acc[mf][2 * np + 1];
      const int hcol = bx * 64 + wc * 32 + np * 16 + lr;
#pragma unroll
      for (int r = 0; r < 4; ++r) {
        const int rl = m0 + wr * 64 + mf * 16 + kc * 4 + r;
        if (rl < ne) {
          const float gg = g[r], uu = u[r];
          const float hv = gg / (1.f + __expf(-gg)) * uu;
          hbuf[(size_t)(off + rl) * HH + hcol] = f2bf(hv);
        }
      }
    }
#undef G1_ISSUE_B
#undef G1_ISSUE_A
#undef G1_WRITE_B
#undef G1_COMPUTE
}

// ---------------- GEMM2: h(bf16) @ w3(fp32, transposed in-kernel) * prob -> atomicAdd out ----
// BM=128, BN=128 d-cols, BK=64; 4 waves (2Mx2N); same counted pipeline; K=2048.
__global__ __launch_bounds__(256) void gemm2_k(
    const unsigned short* __restrict__ hbuf, const float* __restrict__ w3,
    const int* __restrict__ counts, const int* __restrict__ perm,
    const float* __restrict__ prow, float* __restrict__ out) {
  const int bx = blockIdx.x & 7;
  int e, m0, off, ne;
  if (!decode128(counts, blockIdx.x >> 3, e, m0, off, ne)) return;
  const int n1 = bx * 128;

  extern __shared__ __align__(16) unsigned short lds[];
  // shorts: A buf b: b*8192 ; B buf b: 16384 + b*9216 (128 rows x 72)

  const int tid = threadIdx.x, lane = tid & 63, wv = tid >> 6;
  const int srow = lane >> 3;
  const int schunk = ((lane & 7) ^ srow) * 8;

  const unsigned short* pA[4];
#pragma unroll
  for (int q = 0; q < 4; ++q) {
    const int row = wv * 32 + q * 8 + srow;
    pA[q] = hbuf + (size_t)(off + min(m0 + row, ne - 1)) * HH + schunk;
  }
  const int kb = tid >> 4, nb = tid & 15;
  const float* pB1 = w3 + ((size_t)e * HH + 4 * kb) * DD + n1 + 4 * nb;
  const float* pB2 = pB1 + 64;

  const int wr = wv >> 1, wc = wv & 1;
  const int lr = lane & 15, kc = lane >> 4;

  f32x4 acc[4][4];
#pragma unroll
  for (int a = 0; a < 4; ++a)
#pragma unroll
    for (int b = 0; b < 4; ++b) acc[a][b] = f32x4{0.f, 0.f, 0.f, 0.f};

  float4 B1v[4], B2v[4];

#define G2_ISSUE_B()                                                      \
  do {                                                                    \
    B1v[0] = *(const float4*)(pB1);                                       \
    B1v[1] = *(const float4*)(pB1 + DD);                                  \
    B1v[2] = *(const float4*)(pB1 + 2 * DD);                              \
    B1v[3] = *(const float4*)(pB1 + 3 * DD);                              \
    B2v[0] = *(const float4*)(pB2);                                       \
    B2v[1] = *(const float4*)(pB2 + DD);                                  \
    B2v[2] = *(const float4*)(pB2 + 2 * DD);                              \
    B2v[3] = *(const float4*)(pB2 + 3 * DD);                              \
    pB1 += (size_t)64 * DD; pB2 += (size_t)64 * DD;                       \
  } while (0)

#define G2_ISSUE_A(b)                                                     \
  do {                                                                    \
    _Pragma("unroll")                                                     \
    for (int q = 0; q < 4; ++q) {                                         \
      gload16(pA[q], lds + (b) * 8192 + (wv * 32 + q * 8) * 64);          \
      pA[q] += 64;                                                        \
    }                                                                     \
  } while (0)

// rows: B1v -> 4nb+c ; B2v -> 64+4nb+c (same (row>>2)&7 = nb&7 swizzle operand)
#define G2_WRITE_B(b)                                                     \
  do {                                                                    \
    BPACK4(B1v, 16384 + (b) * 9216);                                      \
    const int nbs = nb;                                                   \
    {                                                                     \
      const int nb = nbs + 16;  /* rows 64+4*nbs+c ; (row>>2)&7 == nbs&7 */ \
      BPACK4(B2v, 16384 + (b) * 9216);                                    \
    }                                                                     \
  } while (0)

#define G2_COMPUTE(b)                                                     \
  do {                                                                    \
    const unsigned short* Ab = lds + (b) * 8192;                          \
    const unsigned short* Bb = lds + 16384 + (b) * 9216;                  \
    _Pragma("unroll")                                                     \
    for (int kk = 0; kk < 2; ++kk) {                                      \
      bf16x8 af[4], bf[4];                                                \
      _Pragma("unroll")                                                   \
      for (int mf = 0; mf < 4; ++mf)                                      \
        af[mf] = *(const bf16x8*)&Ab[(wr * 64 + mf * 16 + lr) * 64 +      \
                                     ((kk * 4 + kc) ^ (lr & 7)) * 8];     \
      _Pragma("unroll")                                                   \
      for (int nf = 0; nf < 4; ++nf) {                                    \
        const int row = wc * 64 + nf * 16 + lr;                           \
        bf[nf] = *(const bf16x8*)&Bb[row * 72 +                           \
                       ((kk * 4 + kc) ^ ((row >> 2) & 7)) * 8];           \
      }                                                                   \
      _Pragma("unroll")                                                   \
      for (int mf = 0; mf < 4; ++mf)                                      \
        _Pragma("unroll")                                                 \
        for (int nf = 0; nf < 4; ++nf)                                    \
          acc[mf][nf] = __builtin_amdgcn_mfma_f32_16x16x32_bf16(          \
              af[mf], bf[nf], acc[mf][nf], 0, 0, 0);                      \
    }                                                                     \
  } while (0)

  G2_ISSUE_B(); G2_ISSUE_A(0);
  {
    float4 C1v[4], C2v[4];
#pragma unroll
    for (int j = 0; j < 4; ++j) { C1v[j] = B1v[j]; C2v[j] = B2v[j]; }
    G2_ISSUE_B(); G2_ISSUE_A(1);
    VMCNT(16);
    BPACK4(C1v, 16384);
    {
      const int nbs = nb;
      const int nb2 = nbs + 16;
      {
        const int nb = nb2;
        BPACK4(C2v, 16384);
      }
    }
  }
  VMCNT(12);
  LGKM0(); BARX();

  const int NT = HH / 64;
  for (int t = 0; t < NT; ++t) {
    const int cur = t & 1;
    G2_COMPUTE(cur);
    if (t == NT - 1) break;
    BARX();
    VMCNT(4);
    G2_WRITE_B(cur ^ 1);
    if (t + 2 < NT) { G2_ISSUE_B(); G2_ISSUE_A(cur); VMCNT(12); }
    else VMCNT(0);
    LGKM0(); BARX();
  }

  // epilogue: out[tok] += prob * acc (fp32 atomics, commutative)
#pragma unroll
  for (int mf = 0; mf < 4; ++mf)
#pragma unroll
    for (int r = 0; r < 4; ++r) {
      const int rl = m0 + wr * 64 + mf * 16 + kc * 4 + r;
      if (rl < ne) {
        const int tok = perm[off + rl];
        const float p = prow[off + rl];
        float* op = out + (size_t)tok * DD + n1 + wc * 64 + lr;
#pragma unroll
        for (int nf = 0; nf < 4; ++nf)
          atomicAdd(op + nf * 16, p * acc[mf][nf][r]);
      }
    }
#undef G2_ISSUE_B
#undef G2_ISSUE_A
#undef G2_WRITE_B
#undef G2_COMPUTE
}

// ---------------- workspace layout ----------------
#define WS_COUNTS 0
#define WS_TOPI 128
#define WS_TOPP (WS_TOPI + TOK * 2 * 4)
#define WS_PERM (WS_TOPP + TOK * 2 * 4)
#define WS_PROW (WS_PERM + RTOT * 4)
#define WS_XB ((WS_PROW + RTOT * 4 + 255) & ~(size_t)255)
#define WS_H (WS_XB + (size_t)TOK * DD * 2)
// end = WS_H + RTOT*HH*2 ~= 41.5 MB

extern "C" void kernel_launch(void* const* d_in, const int* in_sizes, int n_in,
                              void* d_out, int out_size, void* d_ws, size_t ws_size,
                              hipStream_t stream) {
  const float* x = (const float*)d_in[0];
  const float* gw = (const float*)d_in[1];
  const float* w1 = (const float*)d_in[2];
  const float* w2 = (const float*)d_in[3];
  const float* w3 = (const float*)d_in[4];
  float* out = (float*)d_out;
  char* ws = (char*)d_ws;

  int* counts = (int*)(ws + WS_COUNTS);
  int* topi = (int*)(ws + WS_TOPI);
  float* topp = (float*)(ws + WS_TOPP);
  int* perm = (int*)(ws + WS_PERM);
  float* prow = (float*)(ws + WS_PROW);
  unsigned short* Xb = (unsigned short*)(ws + WS_XB);
  unsigned short* hbuf = (unsigned short*)(ws + WS_H);

  hipFuncSetAttribute((const void*)gemm1_k, hipFuncAttributeMaxDynamicSharedMemorySize, 69632);
  hipFuncSetAttribute((const void*)gemm2_k, hipFuncAttributeMaxDynamicSharedMemorySize, 69632);

  hipMemsetAsync(ws, 0, 128, stream);
  hipMemsetAsync(out, 0, (size_t)out_size * sizeof(float), stream);
  router_k<<<TOK / 4, 256, 0, stream>>>(x, gw, Xb, topi, topp, counts);
  compact_k<<<NE, 256, 0, stream>>>(topi, topp, counts, perm, prow);
  gemm1_k<<<MAXT1 * 32, 256, 69632, stream>>>(Xb, w1, w2, counts, perm, hbuf);
  gemm2_k<<<MAXT1 * 8, 256, 69632, stream>>>(hbuf, w3, counts, perm, prow, out);
}

// Round 17
// 357.403 us; speedup vs baseline: 1.0611x; 1.0597x over previous
//
#include <hip/hip_runtime.h>
#include <hip/hip_bf16.h>

// B=2,S=2048 -> T=4096 tokens, D=1024, H=2048, E=8, top_k=2
#define TOK 4096
#define DD 1024
#define HH 2048
#define NE 8
#define RTOT (TOK * 2)
#define MAXT1 72   // max Sum ceil(ne/128) = 64 + 7 (+1 pad)

typedef __attribute__((ext_vector_type(8))) short bf16x8;
typedef __attribute__((ext_vector_type(4))) float f32x4;

static __device__ __forceinline__ unsigned short f2bf(float f) {
  union { float f; unsigned int u; } v; v.f = f;
  unsigned int r = v.u + 0x7fffu + ((v.u >> 16) & 1u);
  return (unsigned short)(r >> 16);
}

// async global->LDS, 16B/lane; LDS dest = wave-uniform base + lane*16
static __device__ __forceinline__ void gload16(const unsigned short* g, unsigned short* l) {
  __builtin_amdgcn_global_load_lds(
      (const __attribute__((address_space(1))) unsigned int*)g,
      (__attribute__((address_space(3))) unsigned int*)l, 16, 0, 0);
}

// packed f32x2 -> bf16x2 (RNE), single HW instruction
#define CVT(d, lo, hi) asm("v_cvt_pk_bf16_f32 %0, %1, %2" : "=v"(d) : "v"(lo), "v"(hi))

#define BARX() do { asm volatile("" ::: "memory"); __builtin_amdgcn_s_barrier(); asm volatile("" ::: "memory"); } while (0)
#define VMCNT8() asm volatile("s_waitcnt vmcnt(8)" ::: "memory")
#define VMCNT0() asm volatile("s_waitcnt vmcnt(0)" ::: "memory")

// ---------------- fused pre-kernel: router (blocks 0..1023) + transpose (1024..4095) ----
// R17: 4 ROW-adjacent 64x64 tiles per transpose block -> each output row receives one
// 512B-aligned contiguous chunk from a single block (no 256B line shared across blocks,
// killing the HBM partial-line RMW that made FETCH==WRITE==106MB in R11-R15).
__global__ __launch_bounds__(256) void pre_k(
    const float* __restrict__ x, const float* __restrict__ gw,
    unsigned short* __restrict__ xb, int* __restrict__ topi, float* __restrict__ topp,
    int* __restrict__ counts,
    const float* __restrict__ w1, const float* __restrict__ w2, const float* __restrict__ w3,
    unsigned short* __restrict__ wgu, unsigned short* __restrict__ w3t) {
  __shared__ unsigned short tbuf[64 * 288];   // [crow 0..63][tile 0..3][72]
  const int tid = threadIdx.x;
  const int lane = tid & 63, wv = tid >> 6;

  if (blockIdx.x < 1024) {
    // ---- router ----
    const int t = blockIdx.x * 4 + wv;
    const float4* xr = (const float4*)(x + (size_t)t * DD);
    unsigned int* xw = (unsigned int*)(xb + (size_t)t * DD);
    float acc[NE];
#pragma unroll
    for (int e = 0; e < NE; ++e) acc[e] = 0.f;
#pragma unroll
    for (int i = 0; i < 4; ++i) {
      const float4 xv = xr[i * 64 + lane];
      unsigned int p0, p1;
      CVT(p0, xv.x, xv.y);
      CVT(p1, xv.z, xv.w);
      xw[(i * 64 + lane) * 2] = p0;
      xw[(i * 64 + lane) * 2 + 1] = p1;
#pragma unroll
      for (int e = 0; e < NE; ++e) {
        const float4 gv = ((const float4*)(gw + (size_t)e * DD))[i * 64 + lane];
        acc[e] += xv.x * gv.x + xv.y * gv.y + xv.z * gv.z + xv.w * gv.w;
      }
    }
#pragma unroll
    for (int e = 0; e < NE; ++e)
#pragma unroll
      for (int s = 32; s > 0; s >>= 1) acc[e] += __shfl_xor(acc[e], s, 64);
    if (lane == 0) {
      int i0 = 0; float v0 = acc[0];
#pragma unroll
      for (int e = 1; e < NE; ++e) if (acc[e] > v0) { v0 = acc[e]; i0 = e; }
      int i1 = -1; float v1 = -1e30f;
#pragma unroll
      for (int e = 0; e < NE; ++e) if (e != i0 && acc[e] > v1) { v1 = acc[e]; i1 = e; }
      const float ex = __expf(v1 - v0);
      const float inv = 1.f / (1.f + ex);
      topi[t * 2] = i0; topi[t * 2 + 1] = i1;
      topp[t * 2] = inv; topp[t * 2 + 1] = ex * inv;
      atomicAdd(&counts[i0], 1); atomicAdd(&counts[i1], 1);
    }
    return;
  }

  // ---- transpose: 4 row-adjacent 64x64 tiles (input rows r0..r0+255, cols c0..c0+63) ----
  const int bid = blockIdx.x - 1024;
  const float* in;
  int C, r0, c0, e, mat;
  bool isGU;
  if (bid < 2048) {            // w1/w2 -> wgu
    const int me = bid >> 7;   // 0..15
    mat = me >> 3; e = me & 7;
    const int w = bid & 127;
    const int rg = w >> 5, tc = w & 31;    // 4 row-groups x 32 col-tiles
    in = (mat ? w2 : w1) + (size_t)e * DD * HH;
    C = HH; r0 = rg * 256; c0 = tc * 64;
    isGU = true;
  } else {                     // w3 -> w3t
    const int b2 = bid - 2048;
    e = b2 >> 7; mat = 2;
    const int w = b2 & 127;
    const int rg = w >> 4, tc = w & 15;    // 8 row-groups x 16 col-tiles
    in = w3 + (size_t)e * HH * DD;
    C = DD; r0 = rg * 256; c0 = tc * 64;
    isGU = false;
  }

  const int rs = tid >> 4, cs = tid & 15;
  const float* tbase = in + (size_t)(r0 + rs) * C + c0 + cs * 4;
  float4 ra[4], rb[4];

#define TLOAD(R, ti)                                                      \
  do {                                                                    \
    _Pragma("unroll")                                                     \
    for (int j = 0; j < 4; ++j)                                           \
      R[j] = *(const float4*)(tbase + (size_t)((ti) * 64 + j * 16) * C);  \
  } while (0)

#define TSTAGE(R, ti)                                                     \
  do {                                                                    \
    _Pragma("unroll")                                                     \
    for (int j = 0; j < 4; ++j) {                                         \
      unsigned int d0, d1;                                                \
      CVT(d0, R[j].x, R[j].y);                                            \
      CVT(d1, R[j].z, R[j].w);                                            \
      unsigned short* tb = &tbuf[(cs * 4) * 288 + (ti) * 72 + rs + j * 16]; \
      tb[0] = (unsigned short)d0;                                         \
      tb[288] = (unsigned short)(d0 >> 16);                               \
      tb[576] = (unsigned short)d1;                                       \
      tb[864] = (unsigned short)(d1 >> 16);                               \
    }                                                                     \
  } while (0)

  TLOAD(ra, 0);
  TLOAD(rb, 1);
  TSTAGE(ra, 0);
  TLOAD(ra, 2);
  TSTAGE(rb, 1);
  TLOAD(rb, 3);
  TSTAGE(ra, 2);
  TSTAGE(rb, 3);
  __syncthreads();

  // write: each output row gets 512B contiguous (seg 0..31 x 16B) from this block
#pragma unroll
  for (int q = 0; q < 8; ++q) {
    const int idx = q * 256 + tid;        // 0..2047
    const int crow = idx >> 5, seg = idx & 31;
    const int ti = seg >> 3, s8 = seg & 7;
    const uint4 val = *(const uint4*)&tbuf[crow * 288 + ti * 72 + s8 * 8];
    const int j = c0 + crow;
    const int rr = r0 + ti * 64 + s8 * 8;
    if (isGU) {
      const int R_ = ((j >> 4) << 5) + (j & 15) + mat * 16;
      *(uint4*)&wgu[((size_t)e * 2 * HH + R_) * DD + rr] = val;
    } else {
      *(uint4*)&w3t[((size_t)e * DD + j) * HH + rr] = val;
    }
  }
#undef TLOAD
#undef TSTAGE
}

// ---------------- deterministic sorted compaction (ballot prefix-scan) ----------------
__global__ __launch_bounds__(256) void compact_k(
    const int* __restrict__ topi, const float* __restrict__ topp,
    const int* __restrict__ counts, int* __restrict__ perm, float* __restrict__ prow) {
  const int e = blockIdx.x;
  const int tid = threadIdx.x, lane = tid & 63, wv = tid >> 6;
  __shared__ int wsum[4];
  __shared__ int cbase;
  if (tid == 0) {
    int b = 0;
    for (int i = 0; i < e; ++i) b += counts[i];
    cbase = b;
  }
  __syncthreads();
  for (int c0 = 0; c0 < TOK; c0 += 256) {
    const int t = c0 + tid;
    const int a = topi[2 * t], b = topi[2 * t + 1];
    const int k = (a == e) ? 0 : ((b == e) ? 1 : -1);
    const unsigned long long bal = __ballot(k >= 0);
    const int rank = __popcll(bal & ((1ull << lane) - 1ull));
    if (lane == 0) wsum[wv] = __popcll(bal);
    __syncthreads();
    int woff = 0;
#pragma unroll
    for (int i = 0; i < 4; ++i) if (i < wv) woff += wsum[i];
    const int ctot = wsum[0] + wsum[1] + wsum[2] + wsum[3];
    if (k >= 0) {
      const int pos = cbase + woff + rank;
      perm[pos] = t;
      prow[pos] = topp[2 * t + k];
    }
    __syncthreads();
    if (tid == 0) cbase += ctot;
    __syncthreads();
  }
}

// ---- inline tile decode (BM=128): tix -> (e, m0, off, ne); false if dead ----
static __device__ __forceinline__ bool decode128(const int* counts, int tix,
                                                 int& e, int& m0, int& off, int& ne) {
  int t = tix; off = 0;
  for (e = 0; e < NE; ++e) {
    const int c = counts[e];
    const int nt = (c + 127) >> 7;
    if (t < nt) { m0 = t << 7; ne = c; return true; }
    t -= nt; off += c;
  }
  return false;
}

// ---------------- GEMM1: X(gathered bf16) @ wgu(bf16) -> h = silu(g)*u ----------------
// BM=128, BN=128 wgu-rows (64 h-cols), BK=64; 4 waves (2x2); depth-2 counted-vmcnt dbuf.
__global__ __launch_bounds__(256) void gemm1_k(
    const unsigned short* __restrict__ Xb, const unsigned short* __restrict__ wgu,
    const int* __restrict__ counts, const int* __restrict__ perm,
    unsigned short* __restrict__ hbuf) {
  const int bx = blockIdx.x & 31;
  int e, m0, off, ne;
  if (!decode128(counts, blockIdx.x >> 5, e, m0, off, ne)) return;

  __shared__ unsigned short As[2][128 * 64];
  __shared__ unsigned short Bs[2][128 * 64];

  const int tid = threadIdx.x, lane = tid & 63, wv = tid >> 6;
  const int srow = lane >> 3;
  const int schunk = ((lane & 7) ^ srow) * 8;

  const unsigned short* pA[4];
  const unsigned short* pB[4];
#pragma unroll
  for (int q = 0; q < 4; ++q) {
    const int row = wv * 32 + q * 8 + srow;
    pA[q] = Xb + (size_t)perm[off + min(m0 + row, ne - 1)] * DD + schunk;
    pB[q] = wgu + ((size_t)e * 2 * HH + bx * 128 + row) * DD + schunk;
  }

  const int wr = wv >> 1, wc = wv & 1;
  const int lr = lane & 15, kc = lane >> 4;

  f32x4 acc[4][4];
#pragma unroll
  for (int a = 0; a < 4; ++a)
#pragma unroll
    for (int b = 0; b < 4; ++b) acc[a][b] = f32x4{0.f, 0.f, 0.f, 0.f};

#define G1_ISSUE(b)                                                       \
  do {                                                                    \
    _Pragma("unroll")                                                     \
    for (int q = 0; q < 4; ++q) {                                         \
      gload16(pA[q], &As[b][(wv * 32 + q * 8) * 64]); pA[q] += 64;        \
      gload16(pB[q], &Bs[b][(wv * 32 + q * 8) * 64]); pB[q] += 64;        \
    }                                                                     \
  } while (0)

#define G1_COMPUTE(b)                                                     \
  do {                                                                    \
    _Pragma("unroll")                                                     \
    for (int kk = 0; kk < 2; ++kk) {                                      \
      bf16x8 af[4], bf[4];                                                \
      _Pragma("unroll")                                                   \
      for (int mf = 0; mf < 4; ++mf)                                      \
        af[mf] = *(const bf16x8*)&As[b][(wr * 64 + mf * 16 + lr) * 64 +   \
                                       ((kk * 4 + kc) ^ (lr & 7)) * 8];   \
      _Pragma("unroll")                                                   \
      for (int nf = 0; nf < 4; ++nf)                                      \
        bf[nf] = *(const bf16x8*)&Bs[b][(wc * 64 + nf * 16 + lr) * 64 +   \
                                       ((kk * 4 + kc) ^ (lr & 7)) * 8];   \
      _Pragma("unroll")                                                   \
      for (int mf = 0; mf < 4; ++mf)                                      \
        _Pragma("unroll")                                                 \
        for (int nf = 0; nf < 4; ++nf)                                    \
          acc[mf][nf] = __builtin_amdgcn_mfma_f32_16x16x32_bf16(          \
              af[mf], bf[nf], acc[mf][nf], 0, 0, 0);                      \
    }                                                                     \
  } while (0)

  G1_ISSUE(0);
  G1_ISSUE(1);
  VMCNT8(); BARX();
  for (int t = 0; t < DD / 64; ++t) {
    const int cur = t & 1;
    G1_COMPUTE(cur);
    if (t == DD / 64 - 1) break;
    BARX();                                  // all waves done reading buf[cur]
    if (t < DD / 64 - 2) { G1_ISSUE(cur); VMCNT8(); }   // tile t+2 in; wait t+1
    else VMCNT0();
    BARX();                                  // tile t+1 visible
  }

  // epilogue: nf even = G, nf odd = U (same 16 h-cols)
#pragma unroll
  for (int mf = 0; mf < 4; ++mf)
#pragma unroll
    for (int np = 0; np < 2; ++np) {
      const f32x4 g = acc[mf][2 * np], u = acc[mf][2 * np + 1];
      const int hcol = bx * 64 + (wc * 2 + np) * 16 + lr;
#pragma unroll
      for (int r = 0; r < 4; ++r) {
        const int rl = m0 + wr * 64 + mf * 16 + kc * 4 + r;
        if (rl < ne) {
          const float gg = g[r], uu = u[r];
          const float hv = gg / (1.f + __expf(-gg)) * uu;
          hbuf[(size_t)(off + rl) * HH + hcol] = f2bf(hv);
        }
      }
    }
#undef G1_ISSUE
#undef G1_COMPUTE
}

// ---------------- GEMM2: h(bf16) @ w3t(bf16) * prob -> atomicAdd into out ----------------
// BM=128, BN=128, BK=64; 4 waves (2x2); depth-2 counted-vmcnt dbuf; K=2048.
__global__ __launch_bounds__(256) void gemm2_k(
    const unsigned short* __restrict__ hbuf, const unsigned short* __restrict__ w3t,
    const int* __restrict__ counts, const int* __restrict__ perm,
    const float* __restrict__ prow, float* __restrict__ out) {
  const int bx = blockIdx.x & 7;
  int e, m0, off, ne;
  if (!decode128(counts, blockIdx.x >> 3, e, m0, off, ne)) return;
  const int n1 = bx * 128;

  __shared__ unsigned short As[2][128 * 64];
  __shared__ unsigned short Bs[2][128 * 64];

  const int tid = threadIdx.x, lane = tid & 63, wv = tid >> 6;
  const int srow = lane >> 3;
  const int schunk = ((lane & 7) ^ srow) * 8;

  const unsigned short* pA[4];
  const unsigned short* pB[4];
#pragma unroll
  for (int q = 0; q < 4; ++q) {
    const int row = wv * 32 + q * 8 + srow;
    pA[q] = hbuf + (size_t)(off + min(m0 + row, ne - 1)) * HH + schunk;
    pB[q] = w3t + ((size_t)e * DD + n1 + row) * HH + schunk;
  }

  const int wr = wv >> 1, wc = wv & 1;
  const int lr = lane & 15, kc = lane >> 4;

  f32x4 acc[4][4];
#pragma unroll
  for (int a = 0; a < 4; ++a)
#pragma unroll
    for (int b = 0; b < 4; ++b) acc[a][b] = f32x4{0.f, 0.f, 0.f, 0.f};

#define G2_ISSUE(b)                                                       \
  do {                                                                    \
    _Pragma("unroll")                                                     \
    for (int q = 0; q < 4; ++q) {                                         \
      gload16(pA[q], &As[b][(wv * 32 + q * 8) * 64]); pA[q] += 64;        \
      gload16(pB[q], &Bs[b][(wv * 32 + q * 8) * 64]); pB[q] += 64;        \
    }                                                                     \
  } while (0)

#define G2_COMPUTE(b)                                                     \
  do {                                                                    \
    _Pragma("unroll")                                                     \
    for (int kk = 0; kk < 2; ++kk) {                                      \
      bf16x8 af[4], bf[4];                                                \
      _Pragma("unroll")                                                   \
      for (int mf = 0; mf < 4; ++mf)                                      \
        af[mf] = *(const bf16x8*)&As[b][(wr * 64 + mf * 16 + lr) * 64 +   \
                                       ((kk * 4 + kc) ^ (lr & 7)) * 8];   \
      _Pragma("unroll")                                                   \
      for (int nf = 0; nf < 4; ++nf)                                      \
        bf[nf] = *(const bf16x8*)&Bs[b][(wc * 64 + nf * 16 + lr) * 64 +   \
                                       ((kk * 4 + kc) ^ (lr & 7)) * 8];   \
      _Pragma("unroll")                                                   \
      for (int mf = 0; mf < 4; ++mf)                                      \
        _Pragma("unroll")                                                 \
        for (int nf = 0; nf < 4; ++nf)                                    \
          acc[mf][nf] = __builtin_amdgcn_mfma_f32_16x16x32_bf16(          \
              af[mf], bf[nf], acc[mf][nf], 0, 0, 0);                      \
    }                                                                     \
  } while (0)

  G2_ISSUE(0);
  G2_ISSUE(1);
  VMCNT8(); BARX();
  for (int t = 0; t < HH / 64; ++t) {
    const int cur = t & 1;
    G2_COMPUTE(cur);
    if (t == HH / 64 - 1) break;
    BARX();
    if (t < HH / 64 - 2) { G2_ISSUE(cur); VMCNT8(); }
    else VMCNT0();
    BARX();
  }

  // epilogue: out[tok] += prob * acc  (fp32 atomic add, commutative -> deterministic)
#pragma unroll
  for (int mf = 0; mf < 4; ++mf)
#pragma unroll
    for (int r = 0; r < 4; ++r) {
      const int rl = m0 + wr * 64 + mf * 16 + kc * 4 + r;
      if (rl < ne) {
        const int tok = perm[off + rl];
        const float p = prow[off + rl];
        float* op = out + (size_t)tok * DD + n1 + wc * 64 + lr;
#pragma unroll
        for (int nf = 0; nf < 4; ++nf)
          atomicAdd(op + nf * 16, p * acc[mf][nf][r]);
      }
    }
#undef G2_ISSUE
#undef G2_COMPUTE
}

// ---------------- workspace layout ----------------
#define WS_COUNTS 0
#define WS_TOPI 128
#define WS_TOPP (WS_TOPI + TOK * 2 * 4)
#define WS_PERM (WS_TOPP + TOK * 2 * 4)
#define WS_PROW (WS_PERM + RTOT * 4)
#define WS_XB ((WS_PROW + RTOT * 4 + 255) & ~(size_t)255)
#define WS_H (WS_XB + (size_t)TOK * DD * 2)
#define WS_WGU (WS_H + (size_t)RTOT * HH * 2)
#define WS_W3T (WS_WGU + (size_t)NE * 2 * HH * DD * 2)
// end = WS_W3T + NE*DD*HH*2 ~= 136 MB

extern "C" void kernel_launch(void* const* d_in, const int* in_sizes, int n_in,
                              void* d_out, int out_size, void* d_ws, size_t ws_size,
                              hipStream_t stream) {
  const float* x = (const float*)d_in[0];
  const float* gw = (const float*)d_in[1];
  const float* w1 = (const float*)d_in[2];
  const float* w2 = (const float*)d_in[3];
  const float* w3 = (const float*)d_in[4];
  float* out = (float*)d_out;
  char* ws = (char*)d_ws;

  int* counts = (int*)(ws + WS_COUNTS);
  int* topi = (int*)(ws + WS_TOPI);
  float* topp = (float*)(ws + WS_TOPP);
  int* perm = (int*)(ws + WS_PERM);
  float* prow = (float*)(ws + WS_PROW);
  unsigned short* Xb = (unsigned short*)(ws + WS_XB);
  unsigned short* hbuf = (unsigned short*)(ws + WS_H);
  unsigned short* wgu = (unsigned short*)(ws + WS_WGU);
  unsigned short* w3t = (unsigned short*)(ws + WS_W3T);

  hipMemsetAsync(ws, 0, 128, stream);
  hipMemsetAsync(out, 0, (size_t)out_size * sizeof(float), stream);
  // fused router (1024 blocks) + row-grouped transpose (3072 blocks, 512B write chunks)
  pre_k<<<1024 + 3072, 256, 0, stream>>>(x, gw, Xb, topi, topp, counts,
                                         w1, w2, w3, wgu, w3t);
  compact_k<<<NE, 256, 0, stream>>>(topi, topp, counts, perm, prow);
  gemm1_k<<<MAXT1 * 32, 256, 0, stream>>>(Xb, wgu, counts, perm, hbuf);
  gemm2_k<<<MAXT1 * 8, 256, 0, stream>>>(hbuf, w3t, counts, perm, prow, out);
}